// Round 19
// baseline (446.311 us; speedup 1.0000x reference)
//
#include <hip/hip_runtime.h>
#include <hip/hip_bf16.h>

#define ENC_DIM 2048
#define DEC_DIM 512
#define ATT_DIM 512
#define NB 256
#define NP 196
#define M_TOT (NB * NP)   // 50176 = 392 * 128
#define BM 128
#define BK 32
#define NSTEP (ENC_DIM / BK)  // 64

typedef __attribute__((ext_vector_type(8))) short short8;
typedef __attribute__((ext_vector_type(4))) float f32x4;

__device__ __forceinline__ void gll16(const void* g, void* l) {
    __builtin_amdgcn_global_load_lds((const __attribute__((address_space(1))) void*)g,
                                     (__attribute__((address_space(3))) void*)l,
                                     16, 0, 0);
}

__device__ __forceinline__ short8 cvt8v(f32x4 x, f32x4 y) {
    union { short8 v; __hip_bfloat16 h[8]; } u;
    u.h[0] = __float2bfloat16(x[0]);
    u.h[1] = __float2bfloat16(x[1]);
    u.h[2] = __float2bfloat16(x[2]);
    u.h[3] = __float2bfloat16(x[3]);
    u.h[4] = __float2bfloat16(y[0]);
    u.h[5] = __float2bfloat16(y[1]);
    u.h[6] = __float2bfloat16(y[2]);
    u.h[7] = __float2bfloat16(y[3]);
    return u.v;
}

// ---------------------------------------------------------------------------
// Kernel 1 (fused prep): blocks [0,512): pack W_enc into Btt tiled:
//   short-offset = S*16384 + fr*512 + kg*128 + l15*8 holds
//   bf16 W[k = S*32+kg*8 .. +8][col = fr*16+l15]
// => the 8KB region for (step S, col-quarter nh) is CONTIGUOUS, so a linear
//    gll copy lands fragment-contiguous in LDS (1KB/frag, conflict-free).
// blocks [512,768): att2f = dec@W_dec + b_dec + b_enc.
// ---------------------------------------------------------------------------
__global__ __launch_bounds__(256) void prep_kernel(const float* __restrict__ W,
                                                   __hip_bfloat16* __restrict__ Btt,
                                                   const float* __restrict__ dec,
                                                   const float* __restrict__ W_dec,
                                                   const float* __restrict__ b_dec,
                                                   const float* __restrict__ b_enc,
                                                   float* __restrict__ att2f) {
    __shared__ float ds[DEC_DIM];
    if (blockIdx.x < 512) {
        const int gid = blockIdx.x * 256 + threadIdx.x;  // 0..131071
        const int s   = gid >> 11;        // K-step 0..63
        const int u   = gid & 2047;       // unit within step
        const int fr  = u >> 6;           // col block 0..31
        const int kg  = (u >> 4) & 3;
        const int l15 = u & 15;
        const int col = fr * 16 + l15;
        const int k0  = s * 32 + kg * 8;
        union { short8 v; __hip_bfloat16 h[8]; } x;
        #pragma unroll
        for (int i = 0; i < 8; ++i)
            x.h[i] = __float2bfloat16(W[(size_t)(k0 + i) * ATT_DIM + col]);
        *(short8*)((short*)Btt + (size_t)gid * 8) = x.v;
    } else {
        const int b = blockIdx.x - 512;
        const int t = threadIdx.x;
        ds[t]       = dec[(size_t)b * DEC_DIM + t];
        ds[t + 256] = dec[(size_t)b * DEC_DIM + t + 256];
        __syncthreads();
        #pragma unroll
        for (int j = 0; j < 2; ++j) {
            const int n = t + j * 256;
            float s = 0.f;
            #pragma unroll 8
            for (int k = 0; k < DEC_DIM; ++k)
                s += ds[k] * W_dec[(size_t)k * ATT_DIM + n];
            att2f[(size_t)b * ATT_DIM + n] = s + b_dec[n] + b_enc[n];
        }
    }
}

// ---------------------------------------------------------------------------
// Kernel 2: partial-e over a 128x128 tile — LITERAL m97 GEOMETRY:
// 256 threads (4 waves, 2Mx2N, wave-tile 64x64, acc 4x4), BK=32,
// BOTH operands staged via global_load_lds width-16 into LDS dbuf (48 KB
// -> 3 blocks/CU, 12 waves/CU: m114 cross-block overlap hides the barrier
// drain — the mechanism behind m97's 37% MfmaUtil). ZERO manual pins
// (r18 A/B: pins were net-harmful). A staged as fp32 (fragment-major
// per-lane gll source mapping), cvt->bf16 at fragment read. B from the
// pre-tiled Btt: 8KB contiguous per (s,nh), linear copy, conflict-free.
// XCD grouping: all 4 N-quarters of an m-tile on one XCD (A hits XCD-L2).
// ---------------------------------------------------------------------------
__global__ __launch_bounds__(256, 3) void e_kernel(const float* __restrict__ enc,
                                                   const short* __restrict__ Btt,
                                                   const float* __restrict__ att2f,
                                                   const float* __restrict__ W_att,
                                                   float* __restrict__ e_part) {
    __shared__ __attribute__((aligned(16))) float AsF[2][4096];  // 2 x 16 KB fp32
    __shared__ __attribute__((aligned(16))) short Bs[2][4096];   // 2 x 8 KB bf16
    __shared__ float ebuf[2][128];

    const int tid  = threadIdx.x;
    const int lane = tid & 63;
    const int wv   = tid >> 6;    // 0..3
    const int wm   = wv >> 1;     // 0..1 : 64-row half
    const int wn   = wv & 1;      // 0..1 : 64-col half
    const int l15  = lane & 15;
    const int kg   = lane >> 4;

    // XCD grouping: grid 1568 = 8 XCDs x 196 slots; o = xcd*196 + slot.
    // 196 % 4 == 0 => each XCD holds complete m-tiles (all 4 quarters).
    const int xcd  = blockIdx.x & 7;
    const int slot = blockIdx.x >> 3;
    const int o    = xcd * 196 + slot;
    const int mt   = o >> 2;      // 0..391
    const int nh   = o & 3;       // 0..3 : 128-col quarter
    const int M0   = mt * BM;
    const int N0   = nh * 128;

    // --- A gll staging: 4 calls/thread; unit u = i*256+tid holds
    //     row = (u>>7)*16 + ((u>>1)&15), k-local = ((u>>5)&3)*8 + (u&1)*4.
    //     LDS float idx = u*4  =>  frag-major [mf][kg][l15][2x4f].
    const float* srcA0; const float* srcA1; const float* srcA2; const float* srcA3;
    {
        const int u0 = tid, u1 = 256 + tid, u2 = 512 + tid, u3 = 768 + tid;
        srcA0 = enc + (size_t)(M0 + (u0 >> 7) * 16 + ((u0 >> 1) & 15)) * ENC_DIM + ((u0 >> 5) & 3) * 8 + (u0 & 1) * 4;
        srcA1 = enc + (size_t)(M0 + (u1 >> 7) * 16 + ((u1 >> 1) & 15)) * ENC_DIM + ((u1 >> 5) & 3) * 8 + (u1 & 1) * 4;
        srcA2 = enc + (size_t)(M0 + (u2 >> 7) * 16 + ((u2 >> 1) & 15)) * ENC_DIM + ((u2 >> 5) & 3) * 8 + (u2 & 1) * 4;
        srcA3 = enc + (size_t)(M0 + (u3 >> 7) * 16 + ((u3 >> 1) & 15)) * ENC_DIM + ((u3 >> 5) & 3) * 8 + (u3 & 1) * 4;
    }
    // --- B gll staging: 2 calls/thread; linear copy of the contiguous 8KB region.
    const short* srcB = Btt + nh * 4096 + tid * 8;

    f32x4 acc[4][4];
    #pragma unroll
    for (int i = 0; i < 4; ++i)
        #pragma unroll
        for (int j = 0; j < 4; ++j)
            acc[i][j] = (f32x4){0.f, 0.f, 0.f, 0.f};

    // ---- prologue: stage step 0 into buf 0 ----
    gll16(srcA0, &AsF[0][(tid      ) * 4]);
    gll16(srcA1, &AsF[0][(256 + tid) * 4]);
    gll16(srcA2, &AsF[0][(512 + tid) * 4]);
    gll16(srcA3, &AsF[0][(768 + tid) * 4]);
    gll16(srcB,        &Bs[0][tid * 8]);
    gll16(srcB + 2048, &Bs[0][2048 + tid * 8]);
    __syncthreads();

    for (int s = 0; s < NSTEP; ++s) {
        const int cur = s & 1;
        const int nxt = cur ^ 1;
        if (s + 1 < NSTEP) {
            const int ko = (s + 1) * BK;
            gll16(srcA0 + ko, &AsF[nxt][(tid      ) * 4]);
            gll16(srcA1 + ko, &AsF[nxt][(256 + tid) * 4]);
            gll16(srcA2 + ko, &AsF[nxt][(512 + tid) * 4]);
            gll16(srcA3 + ko, &AsF[nxt][(768 + tid) * 4]);
            const short* sb = srcB + (size_t)(s + 1) * 16384;
            gll16(sb,        &Bs[nxt][tid * 8]);
            gll16(sb + 2048, &Bs[nxt][2048 + tid * 8]);
        }
        // fragments (A: fp32->bf16 at read; B: contiguous 1KB, conflict-free)
        short8 a[4], bfr[4];
        #pragma unroll
        for (int mf = 0; mf < 4; ++mf) {
            const float* ap = &AsF[cur][(wm * 4 + mf) * 512 + lane * 8];
            a[mf] = cvt8v(*(const f32x4*)ap, *(const f32x4*)(ap + 4));
        }
        #pragma unroll
        for (int nf = 0; nf < 4; ++nf)
            bfr[nf] = *(const short8*)&Bs[cur][((wn * 4 + nf) * 64 + lane) * 8];

        #pragma unroll
        for (int mf = 0; mf < 4; ++mf)
            #pragma unroll
            for (int nf = 0; nf < 4; ++nf)
                acc[mf][nf] = __builtin_amdgcn_mfma_f32_16x16x32_bf16(a[mf], bfr[nf], acc[mf][nf], 0, 0, 0);
        __syncthreads();
    }

    // epilogue: + att2, relu, * W_att, partial reduce over this block's 128 cols
    float wat[4];
    #pragma unroll
    for (int nf = 0; nf < 4; ++nf) wat[nf] = W_att[N0 + wn * 64 + nf * 16 + l15];

    #pragma unroll
    for (int mf = 0; mf < 4; ++mf) {
        #pragma unroll
        for (int rr = 0; rr < 4; ++rr) {
            const int ml = wm * 64 + mf * 16 + kg * 4 + rr;   // local row 0..127
            const int bb = (M0 + ml) / NP;
            const float* arow2 = att2f + (size_t)bb * ATT_DIM + N0 + wn * 64 + l15;
            float sv = 0.f;
            #pragma unroll
            for (int nf = 0; nf < 4; ++nf) {
                float v = acc[mf][nf][rr] + arow2[nf * 16];
                sv += fmaxf(v, 0.f) * wat[nf];
            }
            sv += __shfl_xor(sv, 1);
            sv += __shfl_xor(sv, 2);
            sv += __shfl_xor(sv, 4);
            sv += __shfl_xor(sv, 8);
            if (l15 == 0) ebuf[wn][ml] = sv;
        }
    }
    __syncthreads();
    if (tid < 128)
        e_part[(size_t)nh * M_TOT + M0 + tid] = ebuf[0][tid] + ebuf[1][tid];
}

// ---------------------------------------------------------------------------
// Kernel 3: per-batch softmax over 196 pixels (summing the four e-partials)
// + z[b,:] = sum_p alpha[b,p]*enc[b,p,:]. grid (256,2), float4/thread.
// ---------------------------------------------------------------------------
__global__ __launch_bounds__(256) void z_kernel(const float* __restrict__ enc,
                                                const float* __restrict__ e_part,
                                                float* __restrict__ z,
                                                float* __restrict__ alpha) {
    const int b  = blockIdx.x;
    const int cb = blockIdx.y;
    const int t  = threadIdx.x;
    __shared__ float al[NP];
    __shared__ float red[4];

    float ev = -1e30f;
    if (t < NP) {
        const size_t idx = (size_t)b * NP + t;
        ev = e_part[idx] + e_part[M_TOT + idx] + e_part[2 * (size_t)M_TOT + idx] +
             e_part[3 * (size_t)M_TOT + idx];
    }
    float m = ev;
    #pragma unroll
    for (int o = 32; o > 0; o >>= 1) m = fmaxf(m, __shfl_xor(m, o));
    if ((t & 63) == 0) red[t >> 6] = m;
    __syncthreads();
    m = fmaxf(fmaxf(red[0], red[1]), fmaxf(red[2], red[3]));
    __syncthreads();
    float ex = (t < NP) ? __expf(ev - m) : 0.f;
    float s = ex;
    #pragma unroll
    for (int o = 32; o > 0; o >>= 1) s += __shfl_xor(s, o);
    if ((t & 63) == 0) red[t >> 6] = s;
    __syncthreads();
    s = red[0] + red[1] + red[2] + red[3];
    const float a = ex * (1.0f / s);
    if (t < NP) {
        al[t] = a;
        if (cb == 0) alpha[(size_t)b * NP + t] = a;
    }
    __syncthreads();

    const int c0 = cb * 1024 + t * 4;
    const float4* ep = (const float4*)(enc + (size_t)b * NP * ENC_DIM + c0);
    float4 z0 = make_float4(0.f, 0.f, 0.f, 0.f);
    float4 z1 = make_float4(0.f, 0.f, 0.f, 0.f);
    #pragma unroll 4
    for (int p = 0; p < NP; p += 2) {
        const float a0 = al[p];
        const float a1 = al[p + 1];
        const float4 v0 = ep[(size_t)p * (ENC_DIM / 4)];
        const float4 v1 = ep[(size_t)(p + 1) * (ENC_DIM / 4)];
        z0.x += a0 * v0.x; z0.y += a0 * v0.y; z0.z += a0 * v0.z; z0.w += a0 * v0.w;
        z1.x += a1 * v1.x; z1.y += a1 * v1.y; z1.z += a1 * v1.z; z1.w += a1 * v1.w;
    }
    z0.x += z1.x; z0.y += z1.y; z0.z += z1.z; z0.w += z1.w;
    *(float4*)(z + (size_t)b * ENC_DIM + c0) = z0;
}

// ---------------------------------------------------------------------------
extern "C" void kernel_launch(void* const* d_in, const int* in_sizes, int n_in,
                              void* d_out, int out_size, void* d_ws, size_t ws_size,
                              hipStream_t stream) {
    const float* enc   = (const float*)d_in[0];  // (256,196,2048)
    const float* dec   = (const float*)d_in[1];  // (256,512)
    const float* W_enc = (const float*)d_in[2];  // (2048,512)
    const float* b_enc = (const float*)d_in[3];  // (512)
    const float* W_dec = (const float*)d_in[4];  // (512,512)
    const float* b_dec = (const float*)d_in[5];  // (512)
    const float* W_att = (const float*)d_in[6];  // (512,1)
    // d_in[7] = b_att: softmax-invariant, unused.

    float* z     = (float*)d_out;                 // 256*2048
    float* alpha = z + (size_t)NB * ENC_DIM;      // 256*196

    char* ws = (char*)d_ws;
    __hip_bfloat16* Btt = (__hip_bfloat16*)ws;                        // 2 MB
    float* att2f        = (float*)(ws + 2 * 1024 * 1024);             // 512 KB
    float* e_part       = (float*)(ws + 2 * 1024 * 1024 + 512 * 1024);// 4 x 196 KB

    prep_kernel<<<768, 256, 0, stream>>>(W_enc, Btt, dec, W_dec, b_dec, b_enc, att2f);
    e_kernel<<<(M_TOT / BM) * 4, 256, 0, stream>>>(enc, (const short*)Btt, att2f, W_att, e_part);
    z_kernel<<<dim3(NB, 2), 256, 0, stream>>>(enc, e_part, z, alpha);
}

// Round 20
// 294.326 us; speedup vs baseline: 1.5164x; 1.5164x over previous
//
#include <hip/hip_runtime.h>
#include <hip/hip_bf16.h>

#define ENC_DIM 2048
#define DEC_DIM 512
#define ATT_DIM 512
#define NB 256
#define NP 196
#define BK 64
#define NSTEP (ENC_DIM / BK)  // 32

typedef __attribute__((ext_vector_type(8))) short short8;
typedef __attribute__((ext_vector_type(4))) float f32x4;

__device__ __forceinline__ short8 cvt8v(f32x4 x, f32x4 y) {
    union { short8 v; __hip_bfloat16 h[8]; } u;
    u.h[0] = __float2bfloat16(x[0]);
    u.h[1] = __float2bfloat16(x[1]);
    u.h[2] = __float2bfloat16(x[2]);
    u.h[3] = __float2bfloat16(x[3]);
    u.h[4] = __float2bfloat16(y[0]);
    u.h[5] = __float2bfloat16(y[1]);
    u.h[6] = __float2bfloat16(y[2]);
    u.h[7] = __float2bfloat16(y[3]);
    return u.v;
}

// ---------------------------------------------------------------------------
// Kernel 1 (fused prep): blocks [0,512): pack W_enc into Btt tiled:
//   short-offset = S*16384 + fr*512 + kg*128 + l15*8 holds
//   bf16 W[k = S*32+kg*8 .. +8][col = fr*16+l15]   (S = 32-wide K-step)
// => B fragment fr of K-step S is one contiguous 1KB wave load from L2.
// blocks [512,768): att2f = dec@W_dec + b_dec + b_enc.
// ---------------------------------------------------------------------------
__global__ __launch_bounds__(256) void prep_kernel(const float* __restrict__ W,
                                                   __hip_bfloat16* __restrict__ Btt,
                                                   const float* __restrict__ dec,
                                                   const float* __restrict__ W_dec,
                                                   const float* __restrict__ b_dec,
                                                   const float* __restrict__ b_enc,
                                                   float* __restrict__ att2f) {
    __shared__ float ds[DEC_DIM];
    if (blockIdx.x < 512) {
        const int gid = blockIdx.x * 256 + threadIdx.x;  // 0..131071
        const int s   = gid >> 11;        // K-step 0..63
        const int u   = gid & 2047;       // unit within step
        const int fr  = u >> 6;           // col block 0..31
        const int kg  = (u >> 4) & 3;
        const int l15 = u & 15;
        const int col = fr * 16 + l15;
        const int k0  = s * 32 + kg * 8;
        union { short8 v; __hip_bfloat16 h[8]; } x;
        #pragma unroll
        for (int i = 0; i < 8; ++i)
            x.h[i] = __float2bfloat16(W[(size_t)(k0 + i) * ATT_DIM + col]);
        *(short8*)((short*)Btt + (size_t)gid * 8) = x.v;
    } else {
        const int b = blockIdx.x - 512;
        const int t = threadIdx.x;
        ds[t]       = dec[(size_t)b * DEC_DIM + t];
        ds[t + 256] = dec[(size_t)b * DEC_DIM + t + 256];
        __syncthreads();
        #pragma unroll
        for (int j = 0; j < 2; ++j) {
            const int n = t + j * 256;
            float s = 0.f;
            #pragma unroll 8
            for (int k = 0; k < DEC_DIM; ++k)
                s += ds[k] * W_dec[(size_t)k * ATT_DIM + n];
            att2f[(size_t)b * ATT_DIM + n] = s + b_dec[n] + b_enc[n];
        }
    }
}

// ---------------------------------------------------------------------------
// GEMM chunk: MF m-fragments (MF*16 rows at prow0), full N=512, K=2048,
// BK=64 (r20 change: HALF the barriers of r18 -> half the pre-barrier
// vmcnt(0) drains, the cost that scales with nothing else). Per step:
// 8 B-frags (two 32-K halves) loaded at step top (single-buffered in-step;
// L2 latency hides under the 2*MF*4 MFMA cluster), A LDS dbuf + depth-2
// reg pipe. NO manual pins (r18 A/B win).
// ---------------------------------------------------------------------------
template<int MF>
__device__ __forceinline__ void run_chunk(const float* __restrict__ encB,
                                          const short* __restrict__ Btt,
                                          const float* __restrict__ att2b,
                                          const float* __restrict__ W_att,
                                          short (*As)[8192],
                                          float (*ebuf)[128],
                                          float* e_lds,
                                          int prow0, int tid) {
    const int lane = tid & 63;
    const int wv   = tid >> 6;   // 0..7 : 64-col slice
    const int l15  = lane & 15;
    const int kg   = lane >> 4;  // 0..3

    // A staging: thread -> (row = tid>>2 of 128 staged rows, sc = tid&3)
    // stages 16 shorts: (row, k = sc*16 + 0..7) and (row, k = sc*16+8..15)
    const int srow = tid >> 2;
    const int sc   = tid & 3;
    const int p    = prow0 + srow;
    const int cp   = p > (NP - 1) ? (NP - 1) : p;   // clamp pad rows in-bounds
    const float* asrc = encB + (size_t)cp * ENC_DIM + sc * 16;
    // LDS layout [mf][ks(2)][kg(4)][l15(16)][8]: short idx = mf*1024+ks*512+kg*128+l15*8
    const int aw1 = (srow >> 4) * 1024 + (sc >> 1) * 512 + ((sc & 1) * 2) * 128 + (srow & 15) * 8;
    const int aw2 = aw1 + 128;

    // B fragment base: frag nf of 32-step S at short-offset
    //   S*16384 + (wv*4+nf)*512 + kg*128 + l15*8
    const short* pBb = Btt + wv * 2048 + kg * 128 + l15 * 8;

    f32x4 acc[MF][4];
    #pragma unroll
    for (int i = 0; i < MF; ++i)
        #pragma unroll
        for (int j = 0; j < 4; ++j)
            acc[i][j] = (f32x4){0.f, 0.f, 0.f, 0.f};

#define MFMA_CL(BUF, KS, B0, B1, B2, B3)                                                 \
    {                                                                                    \
        const short* Ab = &As[BUF][(KS) * 512];                                          \
        _Pragma("unroll")                                                                \
        for (int mf = 0; mf < MF; ++mf) {                                                \
            const short8 a = *(const short8*)&Ab[mf * 1024 + lane * 8];                  \
            acc[mf][0] = __builtin_amdgcn_mfma_f32_16x16x32_bf16(a, B0, acc[mf][0], 0, 0, 0); \
            acc[mf][1] = __builtin_amdgcn_mfma_f32_16x16x32_bf16(a, B1, acc[mf][1], 0, 0, 0); \
            acc[mf][2] = __builtin_amdgcn_mfma_f32_16x16x32_bf16(a, B2, acc[mf][2], 0, 0, 0); \
            acc[mf][3] = __builtin_amdgcn_mfma_f32_16x16x32_bf16(a, B3, acc[mf][3], 0, 0, 0); \
        }                                                                                \
    }

    // ---- prologue: A(0)->As[0]; A(1)->reg pipe ----
    {
        f32x4 lo = *(const f32x4*)asrc;
        f32x4 hi = *(const f32x4*)(asrc + 4);
        *(short8*)&As[0][aw1] = cvt8v(lo, hi);
        f32x4 lo2 = *(const f32x4*)(asrc + 8);
        f32x4 hi2 = *(const f32x4*)(asrc + 12);
        *(short8*)&As[0][aw2] = cvt8v(lo2, hi2);
    }
    f32x4 avP0 = *(const f32x4*)(asrc + BK);
    f32x4 avP1 = *(const f32x4*)(asrc + BK + 4);
    f32x4 avP2 = *(const f32x4*)(asrc + BK + 8);
    f32x4 avP3 = *(const f32x4*)(asrc + BK + 12);
    __syncthreads();

    for (int s = 0; s < NSTEP; ++s) {
        const int cur = s & 1;
        const int nxt = cur ^ 1;
        // B for this step: two 32-K halves, 8 x 1KB from L2
        const short* pb0 = pBb + (size_t)(2 * s) * 16384;
        const short* pb1 = pb0 + 16384;
        const short8 b00 = *(const short8*)(pb0);
        const short8 b01 = *(const short8*)(pb0 + 512);
        const short8 b02 = *(const short8*)(pb0 + 1024);
        const short8 b03 = *(const short8*)(pb0 + 1536);
        const short8 b10 = *(const short8*)(pb1);
        const short8 b11 = *(const short8*)(pb1 + 512);
        const short8 b12 = *(const short8*)(pb1 + 1024);
        const short8 b13 = *(const short8*)(pb1 + 1536);
        // A(s+2) prefetch
        const int ko = ((s + 2) & (NSTEP - 1)) * BK;
        f32x4 avN0 = *(const f32x4*)(asrc + ko);
        f32x4 avN1 = *(const f32x4*)(asrc + ko + 4);
        f32x4 avN2 = *(const f32x4*)(asrc + ko + 8);
        f32x4 avN3 = *(const f32x4*)(asrc + ko + 12);

        MFMA_CL(cur, 0, b00, b01, b02, b03)
        MFMA_CL(cur, 1, b10, b11, b12, b13)

        // A(s+1) into the other buffer
        *(short8*)&As[nxt][aw1] = cvt8v(avP0, avP1);
        *(short8*)&As[nxt][aw2] = cvt8v(avP2, avP3);
        avP0 = avN0; avP1 = avN1; avP2 = avN2; avP3 = avN3;
        __syncthreads();
    }
#undef MFMA_CL

    // epilogue: + att2, relu, * W_att, reduce over this wave's 64 cols
    float wat[4];
    #pragma unroll
    for (int nf = 0; nf < 4; ++nf) wat[nf] = W_att[wv * 64 + nf * 16 + l15];
    const float* arow2 = att2b + wv * 64 + l15;

    #pragma unroll
    for (int mf = 0; mf < MF; ++mf) {
        #pragma unroll
        for (int rr = 0; rr < 4; ++rr) {
            const int ml = mf * 16 + kg * 4 + rr;   // local row 0..MF*16-1
            float sv = 0.f;
            #pragma unroll
            for (int nf = 0; nf < 4; ++nf) {
                float v = acc[mf][nf][rr] + arow2[nf * 16];
                sv += fmaxf(v, 0.f) * wat[nf];
            }
            sv += __shfl_xor(sv, 1);
            sv += __shfl_xor(sv, 2);
            sv += __shfl_xor(sv, 4);
            sv += __shfl_xor(sv, 8);
            if (l15 == 0) ebuf[wv][ml] = sv;
        }
    }
    __syncthreads();
    if (tid < MF * 16) {
        float sv = 0.f;
        #pragma unroll
        for (int w = 0; w < 8; ++w) sv += ebuf[w][tid];
        const int pp = prow0 + tid;
        if (pp < NP) e_lds[pp] = sv;
    }
    __syncthreads();
}

// ---------------------------------------------------------------------------
// Kernel 2 (FUSED e + softmax + z): one block per batch (grid=256=1/CU).
// (512,1) launch bounds: grid==CU-count means 1 block/CU regardless, so the
// (512,2) register cap in r16/r18 bought nothing — give the allocator room.
// ---------------------------------------------------------------------------
__global__ __launch_bounds__(512, 1) void fused_kernel(const float* __restrict__ enc,
                                                       const short* __restrict__ Btt,
                                                       const float* __restrict__ att2f,
                                                       const float* __restrict__ W_att,
                                                       float* __restrict__ z,
                                                       float* __restrict__ alpha) {
    __shared__ __attribute__((aligned(16))) short As[2][8192];  // 32 KB
    __shared__ float ebuf[8][128];                              // 4 KB
    __shared__ float e_lds[NP];
    __shared__ float al[NP];
    __shared__ float red[8];

    const int tid = threadIdx.x;
    const int b   = blockIdx.x;
    const float* encB  = enc + (size_t)b * NP * ENC_DIM;
    const float* att2b = att2f + (size_t)b * ATT_DIM;

    // ---- phase 1: e-GEMM in two chunks (112 + 96 rows, 196 valid) ----
    run_chunk<7>(encB, Btt, att2b, W_att, As, ebuf, e_lds, 0,   tid);
    run_chunk<6>(encB, Btt, att2b, W_att, As, ebuf, e_lds, 112, tid);

    // ---- phase 2: softmax over 196 pixels (8-wave block reduction) ----
    const int lane = tid & 63;
    const int wv   = tid >> 6;
    float ev = (tid < NP) ? e_lds[tid] : -1e30f;
    float m = ev;
    #pragma unroll
    for (int o = 32; o > 0; o >>= 1) m = fmaxf(m, __shfl_xor(m, o));
    if (lane == 0) red[wv] = m;
    __syncthreads();
    m = red[0];
    #pragma unroll
    for (int w = 1; w < 8; ++w) m = fmaxf(m, red[w]);
    __syncthreads();
    float ex = (tid < NP) ? __expf(ev - m) : 0.f;
    float sum = ex;
    #pragma unroll
    for (int o = 32; o > 0; o >>= 1) sum += __shfl_xor(sum, o);
    if (lane == 0) red[wv] = sum;
    __syncthreads();
    sum = red[0] + red[1] + red[2] + red[3] + red[4] + red[5] + red[6] + red[7];
    const float a = ex * (1.0f / sum);
    if (tid < NP) {
        al[tid] = a;
        alpha[(size_t)b * NP + tid] = a;
    }
    __syncthreads();

    // ---- phase 3: z[b,c] = sum_p al[p] * enc[b,p,c]; enc[b] is L2/L3-hot ----
    const int c0 = tid * 4;   // 512 threads x 4 cols = 2048
    const float4* ep = (const float4*)(encB + c0);
    float4 z0 = make_float4(0.f, 0.f, 0.f, 0.f);
    float4 z1 = make_float4(0.f, 0.f, 0.f, 0.f);
    #pragma unroll 2
    for (int p = 0; p < NP; p += 2) {
        const float a0 = al[p];
        const float a1 = al[p + 1];
        const float4 v0 = ep[(size_t)p * (ENC_DIM / 4)];
        const float4 v1 = ep[(size_t)(p + 1) * (ENC_DIM / 4)];
        z0.x += a0 * v0.x; z0.y += a0 * v0.y; z0.z += a0 * v0.z; z0.w += a0 * v0.w;
        z1.x += a1 * v1.x; z1.y += a1 * v1.y; z1.z += a1 * v1.z; z1.w += a1 * v1.w;
    }
    z0.x += z1.x; z0.y += z1.y; z0.z += z1.z; z0.w += z1.w;
    *(float4*)(z + (size_t)b * ENC_DIM + c0) = z0;
}

// ---------------------------------------------------------------------------
extern "C" void kernel_launch(void* const* d_in, const int* in_sizes, int n_in,
                              void* d_out, int out_size, void* d_ws, size_t ws_size,
                              hipStream_t stream) {
    const float* enc   = (const float*)d_in[0];  // (256,196,2048)
    const float* dec   = (const float*)d_in[1];  // (256,512)
    const float* W_enc = (const float*)d_in[2];  // (2048,512)
    const float* b_enc = (const float*)d_in[3];  // (512)
    const float* W_dec = (const float*)d_in[4];  // (512,512)
    const float* b_dec = (const float*)d_in[5];  // (512)
    const float* W_att = (const float*)d_in[6];  // (512,1)
    // d_in[7] = b_att: softmax-invariant, unused.

    float* z     = (float*)d_out;                 // 256*2048
    float* alpha = z + (size_t)NB * ENC_DIM;      // 256*196

    char* ws = (char*)d_ws;
    __hip_bfloat16* Btt = (__hip_bfloat16*)ws;                // 2 MB
    float* att2f        = (float*)(ws + 2 * 1024 * 1024);     // 512 KB

    prep_kernel<<<768, 256, 0, stream>>>(W_enc, Btt, dec, W_dec, b_dec, b_enc, att2f);
    fused_kernel<<<NB, 512, 0, stream>>>(enc, (const short*)Btt, att2f, W_att, z, alpha);
}

// Round 21
// 264.239 us; speedup vs baseline: 1.6890x; 1.1139x over previous
//
#include <hip/hip_runtime.h>
#include <hip/hip_bf16.h>

#define ENC_DIM 2048
#define DEC_DIM 512
#define ATT_DIM 512
#define NB 256
#define NP 196
#define BK 32
#define NSTEP (ENC_DIM / BK)  // 64

typedef __attribute__((ext_vector_type(8))) short short8;
typedef __attribute__((ext_vector_type(4))) float f32x4;

__device__ __forceinline__ short8 cvt8v(f32x4 x, f32x4 y) {
    union { short8 v; __hip_bfloat16 h[8]; } u;
    u.h[0] = __float2bfloat16(x[0]);
    u.h[1] = __float2bfloat16(x[1]);
    u.h[2] = __float2bfloat16(x[2]);
    u.h[3] = __float2bfloat16(x[3]);
    u.h[4] = __float2bfloat16(y[0]);
    u.h[5] = __float2bfloat16(y[1]);
    u.h[6] = __float2bfloat16(y[2]);
    u.h[7] = __float2bfloat16(y[3]);
    return u.v;
}

// ---------------------------------------------------------------------------
// Kernel 1 (fused prep): blocks [0,512): pack W_enc into Btt tiled:
//   short-offset = S*16384 + fr*512 + kg*128 + l15*8 holds
//   bf16 W[k = S*32+kg*8 .. +8][col = fr*16+l15]
// => B fragment fr of K-step S is one contiguous 1KB wave load from L2.
// blocks [512,768): att2f = dec@W_dec + b_dec + b_enc.
// ---------------------------------------------------------------------------
__global__ __launch_bounds__(256) void prep_kernel(const float* __restrict__ W,
                                                   __hip_bfloat16* __restrict__ Btt,
                                                   const float* __restrict__ dec,
                                                   const float* __restrict__ W_dec,
                                                   const float* __restrict__ b_dec,
                                                   const float* __restrict__ b_enc,
                                                   float* __restrict__ att2f) {
    __shared__ float ds[DEC_DIM];
    if (blockIdx.x < 512) {
        const int gid = blockIdx.x * 256 + threadIdx.x;  // 0..131071
        const int s   = gid >> 11;        // K-step 0..63
        const int u   = gid & 2047;       // unit within step
        const int fr  = u >> 6;           // col block 0..31
        const int kg  = (u >> 4) & 3;
        const int l15 = u & 15;
        const int col = fr * 16 + l15;
        const int k0  = s * 32 + kg * 8;
        union { short8 v; __hip_bfloat16 h[8]; } x;
        #pragma unroll
        for (int i = 0; i < 8; ++i)
            x.h[i] = __float2bfloat16(W[(size_t)(k0 + i) * ATT_DIM + col]);
        *(short8*)((short*)Btt + (size_t)gid * 8) = x.v;
    } else {
        const int b = blockIdx.x - 512;
        const int t = threadIdx.x;
        ds[t]       = dec[(size_t)b * DEC_DIM + t];
        ds[t + 256] = dec[(size_t)b * DEC_DIM + t + 256];
        __syncthreads();
        #pragma unroll
        for (int j = 0; j < 2; ++j) {
            const int n = t + j * 256;
            float s = 0.f;
            #pragma unroll 8
            for (int k = 0; k < DEC_DIM; ++k)
                s += ds[k] * W_dec[(size_t)k * ATT_DIM + n];
            att2f[(size_t)b * ATT_DIM + n] = s + b_dec[n] + b_enc[n];
        }
    }
}

// ---------------------------------------------------------------------------
// GEMM chunk: MF m-fragments (MF*16 rows at prow0), full N=512, K=2048.
// NO-PINS (r18 A/B win: manual sched_barrier/waitcnt/setprio cost 26us —
// m141's lesson): plain __syncthreads(); compiler emits counted waitcnts.
// B: L2->reg named double-buffer, prefetch issued before the MFMA cluster.
// A: reg-staged fp32->bf16->LDS dbuf, depth ~2.
// ---------------------------------------------------------------------------
template<int MF>
__device__ __forceinline__ void run_chunk(const float* __restrict__ encB,
                                          const short* __restrict__ Btt,
                                          const float* __restrict__ att2b,
                                          const float* __restrict__ W_att,
                                          short (*As)[4096],
                                          float (*ebuf)[128],
                                          float* e_lds,
                                          int prow0, int tid) {
    const int lane = tid & 63;
    const int wv   = tid >> 6;   // 0..7 : 64-col slice
    const int l15  = lane & 15;
    const int kg   = lane >> 4;  // 0..3

    // A staging: thread -> (row = tid>>2 of 128 staged rows, k-chunk = tid&3)
    const int srow = tid >> 2;
    const int p    = prow0 + srow;
    const int cp   = p > (NP - 1) ? (NP - 1) : p;   // clamp pad rows in-bounds
    const float* asrc = encB + (size_t)cp * ENC_DIM + (tid & 3) * 8;
    // LDS short index: [mf=srow>>4][kg=tid&3][l15=srow&15][8]
    const int awr = (srow >> 4) * 512 + (tid & 3) * 128 + (srow & 15) * 8;

    // B fragment base: frag nf of step s at short-offset
    //   s*16384 + (wv*4+nf)*512 + kg*128 + l15*8
    const short* pBb = Btt + wv * 2048 + kg * 128 + l15 * 8;

    f32x4 acc[MF][4];
    #pragma unroll
    for (int i = 0; i < MF; ++i)
        #pragma unroll
        for (int j = 0; j < 4; ++j)
            acc[i][j] = (f32x4){0.f, 0.f, 0.f, 0.f};

#define MFMA_CL(BUF, B0, B1, B2, B3)                                                     \
    {                                                                                    \
        const short* Ab = &As[BUF][0];                                                   \
        _Pragma("unroll")                                                                \
        for (int mf = 0; mf < MF; ++mf) {                                                \
            const short8 a = *(const short8*)&Ab[mf * 512 + lane * 8];                   \
            acc[mf][0] = __builtin_amdgcn_mfma_f32_16x16x32_bf16(a, B0, acc[mf][0], 0, 0, 0); \
            acc[mf][1] = __builtin_amdgcn_mfma_f32_16x16x32_bf16(a, B1, acc[mf][1], 0, 0, 0); \
            acc[mf][2] = __builtin_amdgcn_mfma_f32_16x16x32_bf16(a, B2, acc[mf][2], 0, 0, 0); \
            acc[mf][3] = __builtin_amdgcn_mfma_f32_16x16x32_bf16(a, B3, acc[mf][3], 0, 0, 0); \
        }                                                                                \
    }

    // ---- prologue: A(0)->As[0]; A(1)->avP; B(0)->c* ----
    {
        f32x4 lo = *(const f32x4*)asrc;
        f32x4 hi = *(const f32x4*)(asrc + 4);
        *(short8*)&As[0][awr] = cvt8v(lo, hi);
    }
    f32x4 avPa = *(const f32x4*)(asrc + BK);
    f32x4 avPb = *(const f32x4*)(asrc + BK + 4);
    short8 c0 = *(const short8*)(pBb);
    short8 c1 = *(const short8*)(pBb + 512);
    short8 c2 = *(const short8*)(pBb + 1024);
    short8 c3 = *(const short8*)(pBb + 1536);
    short8 n0, n1, n2, n3;
    __syncthreads();

    for (int s = 0; s < NSTEP; s += 2) {
        // ==== even: read As[0], consume c*; prefetch B(s+1)->n*, A(s+2) ====
        {
            const short* p1 = pBb + (size_t)(s + 1) * 16384;
            n0 = *(const short8*)(p1);
            n1 = *(const short8*)(p1 + 512);
            n2 = *(const short8*)(p1 + 1024);
            n3 = *(const short8*)(p1 + 1536);
            f32x4 avNa = *(const f32x4*)(asrc + (size_t)((s + 2) & 63) * BK);
            f32x4 avNb = *(const f32x4*)(asrc + (size_t)((s + 2) & 63) * BK + 4);
            MFMA_CL(0, c0, c1, c2, c3)
            *(short8*)&As[1][awr] = cvt8v(avPa, avPb);  // A(s+1)
            avPa = avNa; avPb = avNb;
            __syncthreads();
        }
        // ==== odd: read As[1], consume n*; prefetch B(s+2)->c*, A(s+3) ====
        {
            const short* p2 = pBb + (size_t)((s + 2) & 63) * 16384;
            c0 = *(const short8*)(p2);
            c1 = *(const short8*)(p2 + 512);
            c2 = *(const short8*)(p2 + 1024);
            c3 = *(const short8*)(p2 + 1536);
            f32x4 avNa = *(const f32x4*)(asrc + (size_t)((s + 3) & 63) * BK);
            f32x4 avNb = *(const f32x4*)(asrc + (size_t)((s + 3) & 63) * BK + 4);
            MFMA_CL(1, n0, n1, n2, n3)
            *(short8*)&As[0][awr] = cvt8v(avPa, avPb);  // A(s+2)
            avPa = avNa; avPb = avNb;
            __syncthreads();
        }
    }
#undef MFMA_CL

    // epilogue: + att2, relu, * W_att, reduce over this wave's 64 cols
    float wat[4];
    #pragma unroll
    for (int nf = 0; nf < 4; ++nf) wat[nf] = W_att[wv * 64 + nf * 16 + l15];
    const float* arow2 = att2b + wv * 64 + l15;

    #pragma unroll
    for (int mf = 0; mf < MF; ++mf) {
        #pragma unroll
        for (int rr = 0; rr < 4; ++rr) {
            const int ml = mf * 16 + kg * 4 + rr;   // local row 0..MF*16-1
            float sv = 0.f;
            #pragma unroll
            for (int nf = 0; nf < 4; ++nf) {
                float v = acc[mf][nf][rr] + arow2[nf * 16];
                sv += fmaxf(v, 0.f) * wat[nf];
            }
            sv += __shfl_xor(sv, 1);
            sv += __shfl_xor(sv, 2);
            sv += __shfl_xor(sv, 4);
            sv += __shfl_xor(sv, 8);
            if (l15 == 0) ebuf[wv][ml] = sv;
        }
    }
    __syncthreads();
    if (tid < MF * 16) {
        float sv = 0.f;
        #pragma unroll
        for (int w = 0; w < 8; ++w) sv += ebuf[w][tid];
        const int pp = prow0 + tid;
        if (pp < NP) e_lds[pp] = sv;
    }
    __syncthreads();
}

// ---------------------------------------------------------------------------
// Kernel 2 (FUSED e + softmax + z): one block per batch (grid=256=1/CU).
// GEMM chunks {112, 96} rows -> e in LDS -> in-block softmax -> z-phase
// re-reads enc[b] (1.6 MB, L2/L3-hot from the GEMM pass — r16/r18 verified:
// FETCH 441 MB = enc read ~once). enc touches HBM once, not twice.
// ---------------------------------------------------------------------------
__global__ __launch_bounds__(512, 2) void fused_kernel(const float* __restrict__ enc,
                                                       const short* __restrict__ Btt,
                                                       const float* __restrict__ att2f,
                                                       const float* __restrict__ W_att,
                                                       float* __restrict__ z,
                                                       float* __restrict__ alpha) {
    __shared__ __attribute__((aligned(16))) short As[2][4096];  // 16 KB
    __shared__ float ebuf[8][128];                              // 4 KB
    __shared__ float e_lds[NP];
    __shared__ float al[NP];
    __shared__ float red[8];

    const int tid = threadIdx.x;
    const int b   = blockIdx.x;
    const float* encB  = enc + (size_t)b * NP * ENC_DIM;
    const float* att2b = att2f + (size_t)b * ATT_DIM;

    // ---- phase 1: e-GEMM in two chunks (112 + 96 rows, 196 valid) ----
    run_chunk<7>(encB, Btt, att2b, W_att, As, ebuf, e_lds, 0,   tid);
    run_chunk<6>(encB, Btt, att2b, W_att, As, ebuf, e_lds, 112, tid);

    // ---- phase 2: softmax over 196 pixels (8-wave block reduction) ----
    const int lane = tid & 63;
    const int wv   = tid >> 6;
    float ev = (tid < NP) ? e_lds[tid] : -1e30f;
    float m = ev;
    #pragma unroll
    for (int o = 32; o > 0; o >>= 1) m = fmaxf(m, __shfl_xor(m, o));
    if (lane == 0) red[wv] = m;
    __syncthreads();
    m = red[0];
    #pragma unroll
    for (int w = 1; w < 8; ++w) m = fmaxf(m, red[w]);
    __syncthreads();
    float ex = (tid < NP) ? __expf(ev - m) : 0.f;
    float sum = ex;
    #pragma unroll
    for (int o = 32; o > 0; o >>= 1) sum += __shfl_xor(sum, o);
    if (lane == 0) red[wv] = sum;
    __syncthreads();
    sum = red[0] + red[1] + red[2] + red[3] + red[4] + red[5] + red[6] + red[7];
    const float a = ex * (1.0f / sum);
    if (tid < NP) {
        al[tid] = a;
        alpha[(size_t)b * NP + tid] = a;
    }
    __syncthreads();

    // ---- phase 3: z[b,c] = sum_p al[p] * enc[b,p,c]; enc[b] is L2/L3-hot ----
    const int c0 = tid * 4;   // 512 threads x 4 cols = 2048
    const float4* ep = (const float4*)(encB + c0);
    float4 z0 = make_float4(0.f, 0.f, 0.f, 0.f);
    float4 z1 = make_float4(0.f, 0.f, 0.f, 0.f);
    #pragma unroll 2
    for (int p = 0; p < NP; p += 2) {
        const float a0 = al[p];
        const float a1 = al[p + 1];
        const float4 v0 = ep[(size_t)p * (ENC_DIM / 4)];
        const float4 v1 = ep[(size_t)(p + 1) * (ENC_DIM / 4)];
        z0.x += a0 * v0.x; z0.y += a0 * v0.y; z0.z += a0 * v0.z; z0.w += a0 * v0.w;
        z1.x += a1 * v1.x; z1.y += a1 * v1.y; z1.z += a1 * v1.z; z1.w += a1 * v1.w;
    }
    z0.x += z1.x; z0.y += z1.y; z0.z += z1.z; z0.w += z1.w;
    *(float4*)(z + (size_t)b * ENC_DIM + c0) = z0;
}

// ---------------------------------------------------------------------------
extern "C" void kernel_launch(void* const* d_in, const int* in_sizes, int n_in,
                              void* d_out, int out_size, void* d_ws, size_t ws_size,
                              hipStream_t stream) {
    const float* enc   = (const float*)d_in[0];  // (256,196,2048)
    const float* dec   = (const float*)d_in[1];  // (256,512)
    const float* W_enc = (const float*)d_in[2];  // (2048,512)
    const float* b_enc = (const float*)d_in[3];  // (512)
    const float* W_dec = (const float*)d_in[4];  // (512,512)
    const float* b_dec = (const float*)d_in[5];  // (512)
    const float* W_att = (const float*)d_in[6];  // (512,1)
    // d_in[7] = b_att: softmax-invariant, unused.

    float* z     = (float*)d_out;                 // 256*2048
    float* alpha = z + (size_t)NB * ENC_DIM;      // 256*196

    char* ws = (char*)d_ws;
    __hip_bfloat16* Btt = (__hip_bfloat16*)ws;                // 2 MB
    float* att2f        = (float*)(ws + 2 * 1024 * 1024);     // 512 KB

    prep_kernel<<<768, 256, 0, stream>>>(W_enc, Btt, dec, W_dec, b_dec, b_enc, att2f);
    fused_kernel<<<NB, 512, 0, stream>>>(enc, (const short*)Btt, att2f, W_att, z, alpha);
}